// Round 3
// baseline (375.732 us; speedup 1.0000x reference)
//
#include <hip/hip_runtime.h>

// Problem dims: P=64, CIN=16 (z), COUT=16 (v), T=4 (a/b), N=32 (i,j), X=64
#define NP    64
#define NCIN  16
#define NCOUT 16
#define NT    4
#define NN    32
#define NX    64

typedef __attribute__((ext_vector_type(8))) __bf16 bf16x8;
typedef __attribute__((ext_vector_type(4))) float  f32x4;

// pack two fp32 -> packed bf16 pair (round-half-up via +0x8000)
__device__ __forceinline__ unsigned pk_bf16(float lo, float hi) {
    unsigned ulo = __float_as_uint(lo) + 0x8000u;
    unsigned uhi = __float_as_uint(hi) + 0x8000u;
    return __builtin_amdgcn_perm(uhi, ulo, 0x07060302u);
}

// LDS Q buffer layout (dword units): per wave, 16 j-rows of 256 bf16 (128 dw)
// padded to 140 dw (140 mod 32 = 12 -> breaks the 16-way conflict on the
// column-major phase-3 reads; (c, c+8) lanes 2-way alias = free per m136).
#define QROW_DW  140
#define QWAVE_DW (16 * QROW_DW)

// Wave-task = (p, i, j-half of 16). Block = 4 waves = (p, i-pair).
// Phase 2 per atom (p,i,j): Q[z,ab] = sum_x FW[z,x] * (PFi[a,x]*PFj[b,x])
//   via 2x mfma_16x16x32_bf16 (D: col=ab=lane&15, row z=(lane>>4)*4+reg).
// Q packed bf16 -> per-wave LDS as Qb[j][k], k = ab*16 + z (256 k).
// __syncthreads() fence (race fix: in-wave DS RAW is NOT ordered without it
// once the compiler's alias analysis loses the dependency — round-2 bug).
// Phase 3 per wave: out[v, j0..j0+15] = sum_k WW2[v,k] * Qb[k,j]
//   via 8x mfma (A = WW2 frags preloaded, 32 VGPRs; B from ds_read_b128).
__global__ __launch_bounds__(256, 4) void higher_point_kernel(
    const float* __restrict__ FW,   // (P, CIN, N, N, X)
    const float* __restrict__ PF,   // (P, T, N, X)
    const float* __restrict__ W0,   // (T, CIN, COUT)
    const float* __restrict__ W1,   // (T, CIN, COUT)
    const float* __restrict__ BIAS, // (COUT,1,1)
    float* __restrict__ OUT)        // (P, COUT, N, N)
{
    __shared__ unsigned qlds[4 * QWAVE_DW]; // 35840 B

    const int bx    = blockIdx.x;
    const int p     = bx >> 4;
    const int ipair = bx & 15;
    const int tid   = threadIdx.x;
    const int lane  = tid & 63;
    const int wave  = tid >> 6;
    const int i     = ipair * 2 + (wave >> 1);
    const int j0    = (wave & 1) * 16;

    const int c    = lane & 15;
    const int q    = lane >> 4;
    const int aIdx = c >> 2;
    const int bIdx = c & 3;

    unsigned* qbase = qlds + wave * QWAVE_DW;

    // ---- WW2 A-frags (one-time): lane holds v=c, frag m covers k=m*32+q*8+e.
    // k = (a*4+b)*16 + z  ->  a=k>>6, b=(k>>4)&3, z=k&15. w0,w1 are L1/L2-hot.
    bf16x8 wwfrag[8];
    #pragma unroll
    for (int m = 0; m < 8; ++m) {
        union { unsigned u[4]; bf16x8 v; } W;
        #pragma unroll
        for (int e2 = 0; e2 < 4; ++e2) {
            const int k0 = m * 32 + q * 8 + e2 * 2;
            const int k1 = k0 + 1;
            float v0 = W0[((k0 >> 6) * NCIN + (k0 & 15)) * NCOUT + c] *
                       W1[(((k0 >> 4) & 3) * NCIN + (k0 & 15)) * NCOUT + c];
            float v1 = W0[((k1 >> 6) * NCIN + (k1 & 15)) * NCOUT + c] *
                       W1[(((k1 >> 4) & 3) * NCIN + (k1 & 15)) * NCOUT + c];
            W.u[e2] = pk_bf16(v0, v1);
        }
        wwfrag[m] = W.v;
    }

    // ---- PF_i slice (fixed per wave): a=aIdx, x = q*8+e (half0) / +32 (half1)
    float pfi0[8], pfi1[8];
    {
        const float* pib = PF + ((p * NT + aIdx) * NN + i) * NX + q * 8;
        float4 a0 = ((const float4*)pib)[0];
        float4 a1 = ((const float4*)pib)[1];
        float4 b0 = ((const float4*)(pib + 32))[0];
        float4 b1 = ((const float4*)(pib + 32))[1];
        pfi0[0]=a0.x; pfi0[1]=a0.y; pfi0[2]=a0.z; pfi0[3]=a0.w;
        pfi0[4]=a1.x; pfi0[5]=a1.y; pfi0[6]=a1.z; pfi0[7]=a1.w;
        pfi1[0]=b0.x; pfi1[1]=b0.y; pfi1[2]=b0.z; pfi1[3]=b0.w;
        pfi1[4]=b1.x; pfi1[5]=b1.y; pfi1[6]=b1.z; pfi1[7]=b1.w;
    }

    // ---- FW stream: lane reads z=c rows, x-offset q*8; j stride = NX floats
    const float* fw_base = FW + (((p * NCIN + c) * NN + i) * NN + j0) * NX + q * 8;
    const float* pf_jb   = PF + ((p * NT + bIdx) * NN + j0) * NX + q * 8;

    float4 nf0a = ((const float4*)fw_base)[0];
    float4 nf0b = ((const float4*)fw_base)[1];
    float4 nf1a = ((const float4*)(fw_base + 32))[0];
    float4 nf1b = ((const float4*)(fw_base + 32))[1];

    for (int jj = 0; jj < 16; ++jj) {
        float4 f0a = nf0a, f0b = nf0b, f1a = nf1a, f1b = nf1b;
        if (jj < 15) {
            const float* nb = fw_base + (jj + 1) * NX;
            nf0a = ((const float4*)nb)[0];
            nf0b = ((const float4*)nb)[1];
            nf1a = ((const float4*)(nb + 32))[0];
            nf1b = ((const float4*)(nb + 32))[1];
        }
        // PF_j from global (L2-resident, 2 MB total)
        const float* pj = pf_jb + jj * NX;
        float4 pj0a = ((const float4*)pj)[0];
        float4 pj0b = ((const float4*)pj)[1];
        float4 pj1a = ((const float4*)(pj + 32))[0];
        float4 pj1b = ((const float4*)(pj + 32))[1];

        union { unsigned u[4]; bf16x8 v; } A0, A1, B0, B1;
        A0.u[0] = pk_bf16(f0a.x, f0a.y); A0.u[1] = pk_bf16(f0a.z, f0a.w);
        A0.u[2] = pk_bf16(f0b.x, f0b.y); A0.u[3] = pk_bf16(f0b.z, f0b.w);
        A1.u[0] = pk_bf16(f1a.x, f1a.y); A1.u[1] = pk_bf16(f1a.z, f1a.w);
        A1.u[2] = pk_bf16(f1b.x, f1b.y); A1.u[3] = pk_bf16(f1b.z, f1b.w);

        B0.u[0] = pk_bf16(pfi0[0] * pj0a.x, pfi0[1] * pj0a.y);
        B0.u[1] = pk_bf16(pfi0[2] * pj0a.z, pfi0[3] * pj0a.w);
        B0.u[2] = pk_bf16(pfi0[4] * pj0b.x, pfi0[5] * pj0b.y);
        B0.u[3] = pk_bf16(pfi0[6] * pj0b.z, pfi0[7] * pj0b.w);
        B1.u[0] = pk_bf16(pfi1[0] * pj1a.x, pfi1[1] * pj1a.y);
        B1.u[1] = pk_bf16(pfi1[2] * pj1a.z, pfi1[3] * pj1a.w);
        B1.u[2] = pk_bf16(pfi1[4] * pj1b.x, pfi1[5] * pj1b.y);
        B1.u[3] = pk_bf16(pfi1[6] * pj1b.z, pfi1[7] * pj1b.w);

        f32x4 acc = {0.f, 0.f, 0.f, 0.f};
        acc = __builtin_amdgcn_mfma_f32_16x16x32_bf16(A0.v, B0.v, acc, 0, 0, 0);
        acc = __builtin_amdgcn_mfma_f32_16x16x32_bf16(A1.v, B1.v, acc, 0, 0, 0);

        // Q -> LDS bf16. Lane holds Q[z=q*4+r][ab=c] -> k = c*16+q*4+r
        // (4 consecutive k) -> one ds_write_b64 at row jj, dword c*8+q*2.
        uint2 qw;
        qw.x = pk_bf16(acc[0], acc[1]);
        qw.y = pk_bf16(acc[2], acc[3]);
        *(uint2*)(qbase + jj * QROW_DW + c * 8 + q * 2) = qw;
    }

    // Full LDS fence + barrier: guarantees phase-2 ds_writes are drained and
    // visible before any phase-3 ds_read (round-2 replay race fix).
    __syncthreads();

    // ---- Phase 3: B-frag col j=c (row c), k = m*32+q*8+e -> 16 contiguous
    // bytes = 4 dwords -> ds_read_b128 at dword c*QROW_DW + m*16 + q*4.
    f32x4 oacc = {0.f, 0.f, 0.f, 0.f};
    #pragma unroll
    for (int m = 0; m < 8; ++m) {
        union { uint4 u4; bf16x8 v; } B;
        B.u4 = *(const uint4*)(qbase + c * QROW_DW + m * 16 + q * 4);
        oacc = __builtin_amdgcn_mfma_f32_16x16x32_bf16(wwfrag[m], B.v, oacc, 0, 0, 0);
    }

    // D: col = c = j - j0, row v = q*4 + reg. Stores coalesce per 16-lane run.
    #pragma unroll
    for (int r = 0; r < 4; ++r) {
        const int v = q * 4 + r;
        float val = oacc[r] + BIAS[v];
        OUT[((p * NCOUT + v) * NN + i) * NN + j0 + c] = val > 0.f ? val : 0.f;
    }
}

extern "C" void kernel_launch(void* const* d_in, const int* in_sizes, int n_in,
                              void* d_out, int out_size, void* d_ws, size_t ws_size,
                              hipStream_t stream) {
    const float* FW   = (const float*)d_in[0];
    const float* PF   = (const float*)d_in[1];
    const float* W0   = (const float*)d_in[2];
    const float* W1   = (const float*)d_in[3];
    const float* BIAS = (const float*)d_in[4];
    float* OUT = (float*)d_out;

    // 1024 blocks = 64 p * 16 i-pairs; 4 waves/block = (i-lo/hi) x (j-half)
    hipLaunchKernelGGL(higher_point_kernel, dim3(NP * NN / 2), dim3(256), 0, stream,
                       FW, PF, W0, W1, BIAS, OUT);
}